// Round 8
// baseline (32.816 us; speedup 1.0000x reference)
//
#include <hip/hip_runtime.h>

#define NS 64            // samples = 32 batches * 2 channels
#define HH 640
#define WW 640
#define NPIX (HH * WW)   // 409600
#define TH 320
#define TW 320
#define MINK 10
#define BPS 40           // blocks per sample (16 rows each)
#define TPB 320          // 4 rows x 80 u-slots, 5 waves

// exact scalar bilinear tap (half-pixel centers, edge clamp) — fallback path only
__device__ __forceinline__ float resize_scalar(const float* __restrict__ tgt, int y, int xc) {
    float sy = fmaxf(0.5f * (float)y - 0.25f, 0.0f);
    int y0 = (int)sy;
    float fy = sy - (float)y0;
    int y1 = min(y0 + 1, TH - 1);
    float sx = fmaxf(0.5f * (float)xc - 0.25f, 0.0f);
    int x0 = (int)sx;
    float fx = sx - (float)x0;
    int x1 = min(x0 + 1, TW - 1);
    const float* r0 = tgt + y0 * TW;
    const float* r1 = tgt + y1 * TW;
    float top = (1.0f - fx) * r0[x0] + fx * r0[x1];
    float bot = (1.0f - fx) * r1[x0] + fx * r1[x1];
    return (1.0f - fy) * top + fy * bot;
}

// one iteration's loaded data: 20 VGPRs
struct Frag {
    float4 p0, p1;   // pred row, 8 px
    float4 a4, b4;   // tgt quads, rows y0/y1
    float La, Ra, Lb, Rb;  // clamped edge taps
};

__device__ __forceinline__ void loadFrag(Frag& f, const float* __restrict__ pred,
                                         const float* __restrict__ tgt,
                                         int y, int xq, int xl, int xr, int u) {
    int y0raw = (y >> 1) + (y & 1) - 1;   // y even: y/2-1 (fy=.75); y odd: (y-1)/2 (fy=.25)
    int y0 = max(y0raw, 0);               // y=0 -> both rows 0 (== resize edge semantics)
    int y1 = min(y0raw + 1, TH - 1);      // y=639 -> clamps to 319
    const float* r0 = tgt + y0 * TW;
    const float* r1 = tgt + y1 * TW;
    f.a4 = *reinterpret_cast<const float4*>(r0 + xq);
    f.b4 = *reinterpret_cast<const float4*>(r1 + xq);
    f.La = r0[xl]; f.Ra = r0[xr];
    f.Lb = r1[xl]; f.Rb = r1[xr];
    const float* pr = pred + y * WW + 8 * u;
    f.p0 = *reinterpret_cast<const float4*>(pr);
    f.p1 = *reinterpret_cast<const float4*>(pr + 4);
}

__device__ __forceinline__ void compFrag(const Frag& f, float gy, float fy,
                                         float& sA, float& sP, int& cP) {
    // y-blend 6 source cols
    float mL = gy * f.La + fy * f.Lb;
    float m0 = gy * f.a4.x + fy * f.b4.x;
    float m1 = gy * f.a4.y + fy * f.b4.y;
    float m2 = gy * f.a4.z + fy * f.b4.z;
    float m3 = gy * f.a4.w + fy * f.b4.w;
    float mR = gy * f.Ra + fy * f.Rb;

    // x-interp: out[2t]=0.25*in[t-1]+0.75*in[t]; out[2t+1]=0.75*in[t]+0.25*in[t+1]
    float tv[8];
    tv[0] = 0.25f * mL + 0.75f * m0;
    tv[1] = 0.75f * m0 + 0.25f * m1;
    tv[2] = 0.25f * m0 + 0.75f * m1;
    tv[3] = 0.75f * m1 + 0.25f * m2;
    tv[4] = 0.25f * m1 + 0.75f * m2;
    tv[5] = 0.75f * m2 + 0.25f * m3;
    tv[6] = 0.25f * m2 + 0.75f * m3;
    tv[7] = 0.75f * m3 + 0.25f * mR;
    float pv[8] = {f.p0.x, f.p0.y, f.p0.z, f.p0.w, f.p1.x, f.p1.y, f.p1.z, f.p1.w};
#pragma unroll
    for (int t = 0; t < 8; ++t) {
        float d = pv[t] - tv[t];
        float l = d * d;
        sA += l;
        bool pos = tv[t] > 0.0f;
        sP += pos ? l : 0.0f;
        cP += pos ? 1 : 0;
    }
}

// ---------------- pass 1: per-sample streaming reduction ----------------
// All 32 VMEM loads issued up front and PINNED (sched_barrier) so the
// compiler cannot re-sink them: 32 loads in flight per wave vs 8 before.
__global__ __launch_bounds__(TPB) void k_reduce(const float* __restrict__ x,
                                                const float* __restrict__ ct,
                                                const float* __restrict__ at,
                                                float* __restrict__ partA,
                                                float* __restrict__ partP,
                                                int* __restrict__ partC) {
    int bid = blockIdx.x;
    int s = bid / BPS, blk = bid % BPS;
    int b = s >> 1, c = s & 1;
    const float* pred = x + (size_t)s * NPIX;
    const float* tgt = (c == 0 ? ct : at) + (size_t)b * (TH * TW);

    int tid = threadIdx.x;
    int u = tid % 80;        // output col group: x = 8u..8u+7
    int rr = tid / 80;       // 0..3
    int rbase = blk * 16;

    float fy = (rr & 1) ? 0.25f : 0.75f;   // y parity = rr parity (rbase even)
    float gy = 1.0f - fy;
    int xq = 4 * u;
    int xl = max(xq - 1, 0);
    int xr = min(xq + 4, TW - 1);

    Frag f0, f1, f2, f3;
    loadFrag(f0, pred, tgt, rbase + rr,      xq, xl, xr, u);
    loadFrag(f1, pred, tgt, rbase + rr + 4,  xq, xl, xr, u);
    loadFrag(f2, pred, tgt, rbase + rr + 8,  xq, xl, xr, u);
    loadFrag(f3, pred, tgt, rbase + rr + 12, xq, xl, xr, u);
    __builtin_amdgcn_sched_barrier(0);   // loads may not sink below this point

    float sA = 0.0f, sP = 0.0f;
    int cP = 0;
    compFrag(f0, gy, fy, sA, sP, cP);
    compFrag(f1, gy, fy, sA, sP, cP);
    compFrag(f2, gy, fy, sA, sP, cP);
    compFrag(f3, gy, fy, sA, sP, cP);

    // wave64 shuffle reduce + LDS block reduce (5 waves)
    for (int off = 32; off > 0; off >>= 1) {
        sA += __shfl_down(sA, off);
        sP += __shfl_down(sP, off);
        cP += __shfl_down(cP, off);
    }
    __shared__ float shA[5], shP[5];
    __shared__ int shC[5];
    int w = tid >> 6;
    if ((tid & 63) == 0) { shA[w] = sA; shP[w] = sP; shC[w] = cP; }
    __syncthreads();
    if (tid == 0) {
        float a = 0.0f, p = 0.0f;
        int ci = 0;
        for (int q = 0; q < 5; ++q) { a += shA[q]; p += shP[q]; ci += shC[q]; }
        partA[s * BPS + blk] = a;
        partP[s * BPS + blk] = p;
        partC[s * BPS + blk] = ci;
    }
}

// ---------------- pass 2: single-block tail — sums, OHEM logic, exact
// top-k fallback (never triggered when p ~ N/2, kept for correctness), mean.
__global__ __launch_bounds__(TPB) void k_tail(const float* __restrict__ x,
                                              const float* __restrict__ ct,
                                              const float* __restrict__ at,
                                              const float* __restrict__ partA,
                                              const float* __restrict__ partP,
                                              const int* __restrict__ partC,
                                              float* __restrict__ out) {
    int tid = threadIdx.x;
    __shared__ float lossSh[NS];
    __shared__ int flagSh[NS], pSh[NS];

    if (tid < NS) {
        float a = 0.0f, pp = 0.0f;
        int p = 0;
        const float4* pa4 = reinterpret_cast<const float4*>(partA + tid * BPS);
        const float4* pp4 = reinterpret_cast<const float4*>(partP + tid * BPS);
        const int4*   pc4 = reinterpret_cast<const int4*>(partC + tid * BPS);
#pragma unroll
        for (int q = 0; q < BPS / 4; ++q) {
            float4 va = pa4[q]; a += va.x + va.y + va.z + va.w;
            float4 vp = pp4[q]; pp += vp.x + vp.y + vp.z + vp.w;
            int4 vc = pc4[q]; p += vc.x + vc.y + vc.z + vc.w;
        }
        int k = min((int)((float)p * 3.0f), NPIX - p);  // exact: 3p < 2^24
        pSh[tid] = p;
        flagSh[tid] = (k >= MINK && k < NPIX - p) ? 1 : 0;
        float lossv;
        if (k < MINK) {
            lossv = a / (float)NPIX;
        } else {
            float nn = a - pp;                       // sumNeg
            float ts = (k >= NPIX - p) ? nn : 0.0f;  // flagged samples add topk below
            lossv = pp / (float)max(p, 1) + ts / (float)max(k, 1);
        }
        lossSh[tid] = lossv;
    }
    __syncthreads();

    // exact top-k fallback: 3-pass bit-histogram select over losses of
    // negative-target elements, for any flagged sample (uniform branch).
    __shared__ unsigned int hcnt[2048];
    __shared__ float hsum[2048];
    __shared__ unsigned int selBin, remSh;
    __shared__ float sumTopSh;
    for (int s2 = 0; s2 < NS; ++s2) {
        if (!flagSh[s2]) continue;
        int p2 = pSh[s2];
        int k2 = min((int)((float)p2 * 3.0f), NPIX - p2);
        const float* pred2 = x + (size_t)s2 * NPIX;
        const float* tgt2 = ((s2 & 1) == 0 ? ct : at) + (size_t)(s2 >> 1) * (TH * TW);
        if (tid == 0) { remSh = (unsigned int)k2; sumTopSh = 0.0f; }
        const int shiftv[3] = {21, 10, 0};
        const unsigned int maskv[3] = {0x7FFu, 0x7FFu, 0x3FFu};
        unsigned int prefix = 0;
        for (int pass = 0; pass < 3; ++pass) {
            for (int i = tid; i < 2048; i += TPB) { hcnt[i] = 0u; hsum[i] = 0.0f; }
            __syncthreads();
            for (int e = tid; e < NPIX; e += TPB) {
                int yy = e / WW, xx = e % WW;
                float tv = resize_scalar(tgt2, yy, xx);
                if (tv > 0.0f) continue;       // positives excluded (-inf in ref)
                float d = pred2[e] - tv;
                float l = d * d;               // >= 0: uint bits order-preserving
                unsigned int bits = __float_as_uint(l);
                bool match;
                if (pass == 0) match = true;
                else if (pass == 1) match = ((bits >> 21) == prefix);
                else match = ((bits >> 10) == prefix);
                if (match) {
                    unsigned int bin = (bits >> shiftv[pass]) & maskv[pass];
                    atomicAdd(&hcnt[bin], 1u);
                    atomicAdd(&hsum[bin], l);
                }
            }
            __syncthreads();
            if (tid == 0) {
                unsigned int remS = remSh;
                int nb = (int)maskv[pass] + 1;
                unsigned int cum = 0; float sAb = 0.0f; unsigned int bsel = 0;
                for (int bin = nb - 1; bin >= 0; --bin) {
                    unsigned int cc = hcnt[bin];
                    if (cum + cc >= remS) { bsel = (unsigned int)bin; break; }
                    cum += cc; sAb += hsum[bin];
                }
                selBin = bsel;
                remSh = remS - cum;
                sumTopSh += sAb;
            }
            __syncthreads();
            if (pass == 0) prefix = selBin;
            else if (pass == 1) prefix = (prefix << 11) | selBin;
            __syncthreads();
        }
        if (tid == 0) {
            unsigned int bits = (prefix << 10) | selBin;   // exact k-th largest
            float topk = sumTopSh + (float)remSh * __uint_as_float(bits);
            lossSh[s2] += topk / (float)max(k2, 1);
        }
        __syncthreads();
    }

    if (tid < NS) {
        float lossv = lossSh[tid];
        for (int off = 32; off > 0; off >>= 1) lossv += __shfl_down(lossv, off);
        if (tid == 0) out[0] = lossv / 32.0f;   // mean over B of (char + aff)
    }
}

extern "C" void kernel_launch(void* const* d_in, const int* in_sizes, int n_in,
                              void* d_out, int out_size, void* d_ws, size_t ws_size,
                              hipStream_t stream) {
    const float* x  = (const float*)d_in[0];
    const float* ct = (const float*)d_in[1];
    const float* at = (const float*)d_in[2];
    float* out = (float*)d_out;

    float* partA = (float*)d_ws;                 // NS*BPS floats
    float* partP = partA + NS * BPS;             // NS*BPS floats
    int*   partC = (int*)(partP + NS * BPS);     // NS*BPS ints

    k_reduce<<<dim3(NS * BPS), dim3(TPB), 0, stream>>>(x, ct, at, partA, partP, partC);
    k_tail<<<dim3(1), dim3(TPB), 0, stream>>>(x, ct, at, partA, partP, partC, out);
}